// Round 1
// baseline (2800.150 us; speedup 1.0000x reference)
//
#include <hip/hip_runtime.h>
#include <hip/hip_bf16.h>

// Problem constants: B=2048, T_ENC=96, H=512, T_DEC=48, ATT=14
#define NB 2048
#define NH 512

typedef float f32x4 __attribute__((ext_vector_type(4)));
typedef short bf16x8 __attribute__((ext_vector_type(8)));

__device__ __forceinline__ float sigm(float x) { return 1.0f / (1.0f + __expf(-x)); }
__device__ __forceinline__ float tanhf_(float x) {
  x = fminf(15.0f, fmaxf(-15.0f, x));
  float e = __expf(2.0f * x);
  return (e - 1.0f) / (e + 1.0f);
}

__device__ __forceinline__ void gload_lds16(const ushort* g, ushort* l) {
  __builtin_amdgcn_global_load_lds((const __attribute__((address_space(1))) ushort*)g,
                                   (__attribute__((address_space(3))) ushort*)l, 16, 0, 0);
}

// ---------------- init: fp32->bf16 weight conversion + dec_in0 ----------------
__global__ void init_kernel(const float* __restrict__ WhhE, const float* __restrict__ WhhD,
                            const float* __restrict__ We, const float* __restrict__ Wd,
                            const float* __restrict__ inputs,
                            __hip_bfloat16* __restrict__ oE, __hip_bfloat16* __restrict__ oD,
                            __hip_bfloat16* __restrict__ oWe, __hip_bfloat16* __restrict__ oWd,
                            float* __restrict__ dec_in)
{
  const int NW = 2048 * 512, NS = 512 * 512;
  const int total = 2 * NW + 2 * NS + NB;
  for (int i = blockIdx.x * blockDim.x + threadIdx.x; i < total; i += gridDim.x * blockDim.x) {
    if (i < NW)               oE[i] = __float2bfloat16(WhhE[i]);
    else if (i < 2 * NW)      oD[i - NW] = __float2bfloat16(WhhD[i - NW]);
    else if (i < 2 * NW + NS) oWe[i - 2 * NW] = __float2bfloat16(We[i - 2 * NW]);
    else if (i < 2 * NW + 2 * NS) oWd[i - 2 * NW - NS] = __float2bfloat16(Wd[i - 2 * NW - NS]);
    else { int b = i - 2 * NW - 2 * NS; dec_in[b] = inputs[b * 96 + 95]; }
  }
}

// ---------------- fused LSTM step: gates GEMM + elementwise ----------------
// Tile: 128 batch rows x 32 h-cols x 4 gate strips (=128 gate cols).
// grid = (16 row-blocks, 16 h-blocks), block = 256 (4 waves, each 32 rows x 128 gate cols)
__global__ __launch_bounds__(256) void lstm_step_kernel(
    const ushort* __restrict__ h_in, ushort* __restrict__ h_out,
    float* __restrict__ h_f32, float* __restrict__ c,
    const ushort* __restrict__ Whh, const float* __restrict__ Wih,
    const float* __restrict__ bias, const float* __restrict__ xsrc,
    int xstride, int write_hf32)
{
  __shared__ __align__(16) ushort lA[2][128 * 32];
  __shared__ __align__(16) ushort lB[2][128 * 32];
  const int tid = threadIdx.x;
  const int lane = tid & 63;
  const int w = tid >> 6;
  const int rb = blockIdx.x;
  const int hb = blockIdx.y;

  f32x4 acc[2][8];
#pragma unroll
  for (int m = 0; m < 2; ++m)
#pragma unroll
    for (int n = 0; n < 8; ++n)
#pragma unroll
      for (int v = 0; v < 4; ++v) acc[m][n][v] = 0.0f;

  auto stage = [&](int buf, int kk) {
    const int k0 = kk * 32;
#pragma unroll
    for (int j = 0; j < 2; ++j) {
      int p = w * 128 + j * 64 + lane;       // linear 16B slot
      int row = p >> 2;
      int kc2 = (p & 3) ^ ((row >> 1) & 3);  // inverse-swizzled source slot
      gload_lds16(h_in + (size_t)(rb * 128 + row) * NH + k0 + kc2 * 8,
                  &lA[buf][(w * 128 + j * 64) * 8]);
      int wrow = ((row >> 5) * NH) + hb * 32 + (row & 31); // gate strip -> W_hh row
      gload_lds16(Whh + (size_t)wrow * NH + k0 + kc2 * 8,
                  &lB[buf][(w * 128 + j * 64) * 8]);
    }
  };

  stage(0, 0);
  __syncthreads();
  int cur = 0;
  const int kc = lane >> 4, rl = lane & 15;
  for (int kk = 0; kk < 16; ++kk) {
    if (kk < 15) stage(cur ^ 1, kk + 1);
    bf16x8 a[2], b[8];
#pragma unroll
    for (int m = 0; m < 2; ++m) {
      int row = w * 32 + m * 16 + rl;
      a[m] = *(const bf16x8*)&lA[cur][row * 32 + ((kc ^ ((row >> 1) & 3)) << 3)];
    }
#pragma unroll
    for (int n = 0; n < 8; ++n) {
      int j = n * 16 + rl;
      b[n] = *(const bf16x8*)&lB[cur][j * 32 + ((kc ^ ((j >> 1) & 3)) << 3)];
    }
#pragma unroll
    for (int m = 0; m < 2; ++m)
#pragma unroll
      for (int n = 0; n < 8; ++n)
        acc[m][n] = __builtin_amdgcn_mfma_f32_16x16x32_bf16(a[m], b[n], acc[m][n], 0, 0, 0);
    __syncthreads();
    cur ^= 1;
  }

  // epilogue: gates -> LSTM update. acc[m][s*2+hf] holds gate strip s.
  float xr[2][4];
#pragma unroll
  for (int m = 0; m < 2; ++m)
#pragma unroll
    for (int v = 0; v < 4; ++v) {
      int rg = rb * 128 + w * 32 + m * 16 + (lane >> 4) * 4 + v;
      xr[m][v] = xsrc[(size_t)rg * xstride];
    }
#pragma unroll
  for (int hf = 0; hf < 2; ++hf) {
    int hcol = hb * 32 + hf * 16 + rl;
    float wi0 = Wih[hcol],        bb0 = bias[hcol];
    float wi1 = Wih[512 + hcol],  bb1 = bias[512 + hcol];
    float wi2 = Wih[1024 + hcol], bb2 = bias[1024 + hcol];
    float wi3 = Wih[1536 + hcol], bb3 = bias[1536 + hcol];
#pragma unroll
    for (int m = 0; m < 2; ++m)
#pragma unroll
      for (int v = 0; v < 4; ++v) {
        int rg = rb * 128 + w * 32 + m * 16 + (lane >> 4) * 4 + v;
        float x = xr[m][v];
        float iv = acc[m][0 + hf][v] + x * wi0 + bb0;
        float fv = acc[m][2 + hf][v] + x * wi1 + bb1;
        float gv = acc[m][4 + hf][v] + x * wi2 + bb2;
        float ov = acc[m][6 + hf][v] + x * wi3 + bb3;
        size_t ci = (size_t)rg * NH + hcol;
        float cold = c[ci];
        float cn = sigm(fv) * cold + sigm(iv) * tanhf_(gv);
        float hn = sigm(ov) * tanhf_(cn);
        c[ci] = cn;
        ((__hip_bfloat16*)h_out)[ci] = __float2bfloat16(hn);
        if (write_hf32) h_f32[ci] = hn;
      }
  }
}

// ---------------- decoder attention scores: T = tanh(hp@We^T + hn@Wd^T) ----------------
// Tile: 128 rows x 32 cols; grid (16,16); block 256 (4 waves of 32x32)
__global__ __launch_bounds__(256) void scores_kernel(
    const ushort* __restrict__ hp, const ushort* __restrict__ hn,
    const ushort* __restrict__ We, const ushort* __restrict__ Wd,
    float* __restrict__ T)
{
  __shared__ __align__(16) ushort lA[2][128 * 32];
  __shared__ __align__(16) ushort lB[2][32 * 32];
  const int tid = threadIdx.x, lane = tid & 63, w = tid >> 6;
  const int rb = blockIdx.x, nb = blockIdx.y;
  f32x4 acc[2][2];
#pragma unroll
  for (int m = 0; m < 2; ++m)
#pragma unroll
    for (int n = 0; n < 2; ++n)
#pragma unroll
      for (int v = 0; v < 4; ++v) acc[m][n][v] = 0.0f;

  auto stage = [&](int buf, int kk) {
    const ushort* As = (kk < 16) ? hp : hn;
    const ushort* Bs = (kk < 16) ? We : Wd;
    const int k0 = (kk & 15) * 32;
#pragma unroll
    for (int j = 0; j < 2; ++j) {
      int p = w * 128 + j * 64 + lane;
      int row = p >> 2;
      int kc2 = (p & 3) ^ ((row >> 1) & 3);
      gload_lds16(As + (size_t)(rb * 128 + row) * NH + k0 + kc2 * 8,
                  &lA[buf][(w * 128 + j * 64) * 8]);
    }
    if (w < 2) {
      int p = w * 64 + lane;
      int row = p >> 2;
      int kc2 = (p & 3) ^ ((row >> 1) & 3);
      gload_lds16(Bs + (size_t)(nb * 32 + row) * NH + k0 + kc2 * 8,
                  &lB[buf][(w * 64) * 8]);
    }
  };

  stage(0, 0);
  __syncthreads();
  int cur = 0;
  const int kc = lane >> 4, rl = lane & 15;
  for (int kk = 0; kk < 32; ++kk) {
    if (kk < 31) stage(cur ^ 1, kk + 1);
    bf16x8 a[2], b[2];
#pragma unroll
    for (int m = 0; m < 2; ++m) {
      int row = w * 32 + m * 16 + rl;
      a[m] = *(const bf16x8*)&lA[cur][row * 32 + ((kc ^ ((row >> 1) & 3)) << 3)];
    }
#pragma unroll
    for (int n = 0; n < 2; ++n) {
      int j = n * 16 + rl;
      b[n] = *(const bf16x8*)&lB[cur][j * 32 + ((kc ^ ((j >> 1) & 3)) << 3)];
    }
#pragma unroll
    for (int m = 0; m < 2; ++m)
#pragma unroll
      for (int n = 0; n < 2; ++n)
        acc[m][n] = __builtin_amdgcn_mfma_f32_16x16x32_bf16(a[m], b[n], acc[m][n], 0, 0, 0);
    __syncthreads();
    cur ^= 1;
  }
#pragma unroll
  for (int m = 0; m < 2; ++m)
#pragma unroll
    for (int n = 0; n < 2; ++n)
#pragma unroll
      for (int v = 0; v < 4; ++v) {
        int rg = rb * 128 + w * 32 + m * 16 + (lane >> 4) * 4 + v;
        int col = nb * 32 + n * 16 + rl;
        T[(size_t)rg * NH + col] = tanhf_(acc[m][n][v]);
      }
}

// ---------------- per-row: scores@Wval^T, softmax, output, attn accumulation ----------------
// one wave per batch row; grid 512 x block 256 (4 waves)
__global__ __launch_bounds__(256) void finish_kernel(
    const float* __restrict__ T, const float* __restrict__ h_f32,
    const float* __restrict__ Wval, const float* __restrict__ Wfin,
    const float* __restrict__ bfin, float* __restrict__ out,
    float* __restrict__ dec_in, int t)
{
  const int lane = threadIdx.x & 63;
  const int w = threadIdx.x >> 6;
  const int row = blockIdx.x * 4 + w;
  const float* tr = T + (size_t)row * NH + lane * 8;
  f32x4 t0 = *(const f32x4*)tr;
  f32x4 t1 = *(const f32x4*)(tr + 4);
  float s[14];
#pragma unroll
  for (int a = 0; a < 14; ++a) {
    const float* wr = Wval + a * NH + lane * 8;
    f32x4 w0 = *(const f32x4*)wr;
    f32x4 w1 = *(const f32x4*)(wr + 4);
    float p = 0.0f;
#pragma unroll
    for (int i = 0; i < 4; ++i) p += t0[i] * w0[i] + t1[i] * w1[i];
#pragma unroll
    for (int m = 1; m < 64; m <<= 1) p += __shfl_xor(p, m);
    s[a] = p;
  }
  float mx = s[0];
#pragma unroll
  for (int a = 1; a < 14; ++a) mx = fmaxf(mx, s[a]);
  float e[14];
  float Z = 0.0f;
#pragma unroll
  for (int a = 0; a < 14; ++a) { e[a] = __expf(s[a] - mx); Z += e[a]; }
  float inv = 1.0f / Z;
  float aw = 0.0f;
#pragma unroll
  for (int a = 0; a < 14; ++a) aw += (e[a] * inv) * Wfin[a];
  const float* hr = h_f32 + (size_t)row * NH + lane * 8;
  float hp = 0.0f;
#pragma unroll
  for (int i = 0; i < 8; ++i) hp += hr[i] * Wfin[14 + lane * 8 + i];
#pragma unroll
  for (int m = 1; m < 64; m <<= 1) hp += __shfl_xor(hp, m);
  float outv = aw + hp + bfin[0];
  if (lane == 0) { out[row * 48 + t] = outv; dec_in[row] = outv; }
  float mine = 0.0f;
#pragma unroll
  for (int a = 0; a < 14; ++a) mine = (lane == a) ? e[a] * inv : mine;
  if (lane < 14) out[2048 * 48 + row * 14 + lane] += mine;
}

extern "C" void kernel_launch(void* const* d_in, const int* in_sizes, int n_in,
                              void* d_out, int out_size, void* d_ws, size_t ws_size,
                              hipStream_t stream)
{
  (void)in_sizes; (void)n_in; (void)out_size; (void)ws_size;
  const float* inputs = (const float*)d_in[0];
  // d_in[1] = target_len (48), compile-time constant here
  const float* encWih = (const float*)d_in[2];
  const float* encWhh = (const float*)d_in[3];
  const float* encb   = (const float*)d_in[4];
  const float* decWih = (const float*)d_in[5];
  const float* decWhh = (const float*)d_in[6];
  const float* decb   = (const float*)d_in[7];
  const float* Wenc   = (const float*)d_in[8];
  const float* Wdec   = (const float*)d_in[9];
  const float* Wval   = (const float*)d_in[10];
  const float* Wfin   = (const float*)d_in[11];
  const float* bfin   = (const float*)d_in[12];
  float* out = (float*)d_out;
  char* ws = (char*)d_ws;
  const size_t MB = 1 << 20;
  ushort* WhhE_b = (ushort*)(ws + 0);
  ushort* WhhD_b = (ushort*)(ws + 2 * MB);
  ushort* WencB  = (ushort*)(ws + 4 * MB);
  ushort* WdecB  = (ushort*)(ws + 4 * MB + 512 * 1024);
  ushort* hbuf0  = (ushort*)(ws + 5 * MB);
  ushort* hbuf1  = (ushort*)(ws + 7 * MB);
  float*  cbuf   = (float*)(ws + 9 * MB);
  float*  hf32   = (float*)(ws + 13 * MB);
  float*  Tbuf   = (float*)(ws + 17 * MB);
  float*  dec_in = (float*)(ws + 21 * MB);

  hipMemsetAsync(hbuf0, 0, 2 * MB, stream);               // h0 = 0 (bf16 zero)
  hipMemsetAsync(cbuf, 0, 4 * MB, stream);                // c0 = 0
  hipMemsetAsync(out + 2048 * 48, 0, 2048 * 14 * sizeof(float), stream); // attn accum
  init_kernel<<<1024, 256, 0, stream>>>(encWhh, decWhh, Wenc, Wdec, inputs,
      (__hip_bfloat16*)WhhE_b, (__hip_bfloat16*)WhhD_b,
      (__hip_bfloat16*)WencB, (__hip_bfloat16*)WdecB, dec_in);

  ushort* hb[2] = {hbuf0, hbuf1};
  int p = 0;
  for (int t = 0; t < 96; ++t) {
    lstm_step_kernel<<<dim3(16, 16), 256, 0, stream>>>(
        hb[p], hb[p ^ 1], nullptr, cbuf, WhhE_b, encWih, encb, inputs + t, 96, 0);
    p ^= 1;
  }
  for (int t = 0; t < 48; ++t) {
    lstm_step_kernel<<<dim3(16, 16), 256, 0, stream>>>(
        hb[p], hb[p ^ 1], hf32, cbuf, WhhD_b, decWih, decb, dec_in, 1, 1);
    scores_kernel<<<dim3(16, 16), 256, 0, stream>>>(hb[p], hb[p ^ 1], WencB, WdecB, Tbuf);
    finish_kernel<<<512, 256, 0, stream>>>(Tbuf, hf32, Wval, Wfin, bfin, out, dec_in, t);
    p ^= 1;
  }
}